// Round 4
// baseline (424.340 us; speedup 1.0000x reference)
//
#include <hip/hip_runtime.h>
#include <cstdint>

#define NROW 192
#define NW   262144
#define NT   1024
#define QCAP 1024
#define SEGS_CAP 12288

// ---------- monotone float<->uint transform (total order) ----------
__device__ __forceinline__ uint32_t mono(float x) {
    uint32_t u = __float_as_uint(x);
    return (u & 0x80000000u) ? ~u : (u | 0x80000000u);
}
__device__ __forceinline__ float unmono(uint32_t u) {
    uint32_t v = (u & 0x80000000u) ? (u & 0x7FFFFFFFu) : ~u;
    return __uint_as_float(v);
}
// linear-in-value bin; MUST be the same code in hist and collect sweeps
__device__ __forceinline__ int binof(float x, float lo, float s) {
    float d = (x - lo) * s;
    d = fminf(fmaxf(d, 0.0f), 4095.0f);
    return (int)d;
}

// ---------- block "find bin containing rank" ----------
__device__ void block_select(const uint32_t* hist, int nb, uint32_t rank,
                             uint32_t* sbuf, volatile uint32_t* out, int tid) {
    int per = (nb + NT - 1) / NT;
    int base = tid * per;
    uint32_t s = 0;
    for (int i = 0; i < per; ++i) { int idx = base + i; if (idx < nb) s += hist[idx]; }
    uint32_t p = s;
    int lane = tid & 63;
    #pragma unroll
    for (int off = 1; off < 64; off <<= 1) {
        uint32_t v = __shfl_up(p, off);
        if (lane >= off) p += v;
    }
    int w = tid >> 6;
    if (lane == 63) sbuf[w] = p;
    __syncthreads();
    if (tid == 0) {
        uint32_t acc = 0;
        for (int i = 0; i < 16; ++i) { uint32_t t = sbuf[i]; sbuf[16 + i] = acc; acc += t; }
    }
    __syncthreads();
    uint32_t excl = sbuf[16 + w] + p - s;
    if (rank >= excl && rank < excl + s) {
        uint32_t rem = rank - excl;
        for (int i = 0; i < per; ++i) {
            int idx = base + i;
            if (idx >= nb) break;
            uint32_t c = hist[idx];
            if (rem < c) { out[0] = (uint32_t)idx; out[1] = rem; break; }
            rem -= c;
        }
    }
    __syncthreads();
}

// ---------- exact rank-select among seg[0..cnt) keys, 3-pass LDS radix 11/11/10 ----------
__device__ uint32_t seg_select(const uint32_t* seg, uint32_t cnt, uint32_t rank,
                               uint32_t* hist2, uint32_t* sbuf,
                               volatile uint32_t* out2, int tid) {
    for (int i = tid; i < 2048; i += NT) hist2[i] = 0;
    __syncthreads();
    for (uint32_t i = tid; i < cnt; i += NT) atomicAdd(&hist2[seg[i] >> 21], 1u);
    __syncthreads();
    block_select(hist2, 2048, rank, sbuf, out2, tid);
    uint32_t b1 = out2[0], r1 = out2[1];
    __syncthreads();
    for (int i = tid; i < 2048; i += NT) hist2[i] = 0;
    __syncthreads();
    for (uint32_t i = tid; i < cnt; i += NT) {
        uint32_t k = seg[i];
        if ((k >> 21) == b1) atomicAdd(&hist2[(k >> 10) & 2047u], 1u);
    }
    __syncthreads();
    block_select(hist2, 2048, r1, sbuf, out2, tid);
    uint32_t b2 = out2[0], r2 = out2[1];
    __syncthreads();
    for (int i = tid; i < 1024; i += NT) hist2[i] = 0;
    __syncthreads();
    for (uint32_t i = tid; i < cnt; i += NT) {
        uint32_t k = seg[i];
        if ((k >> 21) == b1 && ((k >> 10) & 2047u) == b2)
            atomicAdd(&hist2[k & 1023u], 1u);
    }
    __syncthreads();
    block_select(hist2, 1024, r2, sbuf, out2, tid);
    uint32_t b3 = out2[0];
    __syncthreads();
    return (b1 << 21) + (b2 << 10) + b3;
}

// ---------- fallback: finish a rank with 2 global sweeps (12-bit mono, proven) ----------
__device__ uint32_t refine_global(const float4* p4, float med, int mode,
                                  uint32_t b1, uint32_t rem,
                                  uint32_t* hist2, uint32_t* sbuf,
                                  volatile uint32_t* out2, int tid) {
    for (int i = tid; i < 2048; i += NT) hist2[i] = 0;
    __syncthreads();
    for (int it = 0; it < 64; ++it) {
        float4 v = p4[tid + it * NT];
        float xs[4] = {v.x, v.y, v.z, v.w};
        #pragma unroll
        for (int c = 0; c < 4; ++c) {
            uint32_t u = mode ? __float_as_uint(fabsf(xs[c] - med)) : mono(xs[c]);
            if ((u >> 20) == b1) atomicAdd(&hist2[(u >> 9) & 2047u], 1u);
        }
    }
    __syncthreads();
    block_select(hist2, 2048, rem, sbuf, out2, tid);
    uint32_t b2 = out2[0], r2 = out2[1];
    __syncthreads();
    for (int i = tid; i < 512; i += NT) hist2[i] = 0;
    __syncthreads();
    for (int it = 0; it < 64; ++it) {
        float4 v = p4[tid + it * NT];
        float xs[4] = {v.x, v.y, v.z, v.w};
        #pragma unroll
        for (int c = 0; c < 4; ++c) {
            uint32_t u = mode ? __float_as_uint(fabsf(xs[c] - med)) : mono(xs[c]);
            if ((u >> 20) == b1 && ((u >> 9) & 2047u) == b2)
                atomicAdd(&hist2[u & 511u], 1u);
        }
    }
    __syncthreads();
    block_select(hist2, 512, r2, sbuf, out2, tid);
    uint32_t b3 = out2[0];
    __syncthreads();
    return (b1 << 20) + (b2 << 9) + b3;
}

// ---------- fallback path: full 12-bit 3-level select (slow, always correct) ----------
// writes w-features into LDS xf[0,1,3,4,5]
__device__ void fb_path(const float4* p4, float* xf,
                        uint32_t* hist, uint32_t* hist2, uint32_t* sbuf,
                        volatile uint32_t* out2, int tid) {
    const uint32_t RANK6[6] = {65535u, 65536u, 131071u, 131072u, 196607u, 196608u};
    for (int i = tid; i < 4096; i += NT) hist[i] = 0;
    __syncthreads();
    for (int it = 0; it < 64; ++it) {
        float4 v = p4[tid + it * NT];
        float xs[4] = {v.x, v.y, v.z, v.w};
        #pragma unroll
        for (int c = 0; c < 4; ++c) atomicAdd(&hist[mono(xs[c]) >> 20], 1u);
    }
    __syncthreads();
    uint32_t bins[6], rems[6];
    for (int k = 0; k < 6; ++k) {
        block_select(hist, 4096, RANK6[k], sbuf, out2, tid);
        bins[k] = out2[0]; rems[k] = out2[1];
        __syncthreads();
    }
    float svv[6];
    for (int k = 0; k < 6; ++k)
        svv[k] = unmono(refine_global(p4, 0.f, 0, bins[k], rems[k], hist2, sbuf, out2, tid));
    if (tid == 0) {
        xf[0] = svv[2];
        xf[3] = 0.25f * svv[0] + 0.75f * svv[1];
        xf[4] = 0.5f  * (svv[2] + svv[3]);
        xf[5] = 0.75f * svv[4] + 0.25f * svv[5];
    }
    float med = svv[2];
    __syncthreads();
    for (int i = tid; i < 4096; i += NT) hist[i] = 0;
    __syncthreads();
    for (int it = 0; it < 64; ++it) {
        float4 v = p4[tid + it * NT];
        float xs[4] = {v.x, v.y, v.z, v.w};
        #pragma unroll
        for (int c = 0; c < 4; ++c)
            atomicAdd(&hist[__float_as_uint(fabsf(xs[c] - med)) >> 20], 1u);
    }
    __syncthreads();
    block_select(hist, 4096, 131071u, sbuf, out2, tid);
    uint32_t mb = out2[0], mr = out2[1];
    __syncthreads();
    uint32_t mu = refine_global(p4, med, 1, mb, mr, hist2, sbuf, out2, tid);
    if (tid == 0) xf[1] = __uint_as_float(mu);
}

// ---------- prefix-sum helpers (hist holds exclusive prefix P after scan) ----------
__device__ __forceinline__ uint32_t Pv(const uint32_t* P, int k) {
    return (k >= 4096) ? (uint32_t)NW : P[k];
}
__device__ __forceinline__ uint32_t wup(float mL, float mR, float tau,
                                        float blo, float bsc, const uint32_t* P) {
    const int bR = binof(mR + tau, blo, bsc);
    const int bL = binof(mL - tau, blo, bsc);
    return Pv(P, bR + 1) - P[bL];
}
__device__ __forceinline__ uint32_t wlow(float mL, float mR, float tau,
                                         float blo, float bsc, const uint32_t* P) {
    const int bR = binof(mL + tau, blo, bsc);
    const int bL = binof(mR - tau, blo, bsc);
    const uint32_t a = P[bR];
    const uint32_t b = Pv(P, bL + 1);
    return (a > b) ? (a - b) : 0u;
}

// ---------- in-LDS bitonic sort of 512 floats; 1024 threads, 1 elem/thread ----------
__device__ void bitonic512w(float* a, int tid) {
    for (int k = 2; k <= 512; k <<= 1) {
        for (int j = k >> 1; j > 0; j >>= 1) {
            __syncthreads();
            if (tid < 512) {
                int i = tid, ixj = i ^ j;
                if (ixj > i) {
                    float x = a[i], y = a[ixj];
                    bool up = ((i & k) == 0);
                    if ((x > y) == up) { a[i] = y; a[ixj] = x; }
                }
            }
        }
    }
    __syncthreads();
}

// ---------- w-row robust stats body: 2 full sweeps, writes xf[0..6,14,15] ----------
__device__ void wstats_body(const float4* __restrict__ p4, float* xf,
                            uint32_t* hist, uint32_t* histB,
                            uint32_t* sbuf, uint32_t* segs,
                            uint32_t* ctrl, float* fctrl, int tid) {
    const int lane = tid & 63, wv = tid >> 6;
    float* fsb = (float*)sbuf;
    volatile uint32_t* out2 = (volatile uint32_t*)(ctrl + 62);

    // ---- P0: contiguous prefix sample (32768 floats) -> linear-bin range ----
    {
        float smin = 1e30f, smax = -1e30f;
        #pragma unroll
        for (int k = 0; k < 8; ++k) {
            float4 v = p4[tid + k * NT];
            smin = fminf(smin, fminf(fminf(v.x, v.y), fminf(v.z, v.w)));
            smax = fmaxf(smax, fmaxf(fmaxf(v.x, v.y), fmaxf(v.z, v.w)));
        }
        #pragma unroll
        for (int off = 32; off > 0; off >>= 1) {
            smin = fminf(smin, __shfl_down(smin, off));
            smax = fmaxf(smax, __shfl_down(smax, off));
        }
        if (lane == 0) { fsb[wv * 2] = smin; fsb[wv * 2 + 1] = smax; }
        __syncthreads();
        if (tid == 0) {
            float mn = 1e30f, mx = -1e30f;
            for (int i = 0; i < 16; ++i) { mn = fminf(mn, fsb[i * 2]); mx = fmaxf(mx, fsb[i * 2 + 1]); }
            float span = mx - mn;
            float lo = mn - 0.0625f * span;
            float s = (span > 0.f) ? 4096.0f / (span * 1.125f) : 0.0f;
            fctrl[0] = lo; fctrl[1] = s;
        }
        __syncthreads();
    }
    const float blo = fctrl[0], bsc = fctrl[1];

    // ---- S1: full sweep — privatized linear hist (2 copies) + sum + exact min/max ----
    for (int i = tid; i < 4096; i += NT) { hist[i] = 0; histB[i] = 0; }
    __syncthreads();
    {
        uint32_t* hsel = (wv & 1) ? histB : hist;   // adjacent waves on different copies
        float sum = 0.f, fmn = 1e30f, fmx = -1e30f;
        for (int it = 0; it < 64; it += 8) {
            float4 a8[8];
            #pragma unroll
            for (int j = 0; j < 8; ++j) a8[j] = p4[tid + (it + j) * NT];
            #pragma unroll
            for (int j = 0; j < 8; ++j) {
                float xs[4] = {a8[j].x, a8[j].y, a8[j].z, a8[j].w};
                #pragma unroll
                for (int c = 0; c < 4; ++c) {
                    float x = xs[c];
                    sum += x;
                    fmn = fminf(fmn, x);
                    fmx = fmaxf(fmx, x);
                    atomicAdd(&hsel[binof(x, blo, bsc)], 1u);
                }
            }
        }
        #pragma unroll
        for (int off = 32; off > 0; off >>= 1) {
            sum += __shfl_down(sum, off);
            fmn = fminf(fmn, __shfl_down(fmn, off));
            fmx = fmaxf(fmx, __shfl_down(fmx, off));
        }
        __syncthreads();
        if (lane == 0) { fsb[wv * 4] = sum; fsb[wv * 4 + 1] = fmn; fsb[wv * 4 + 2] = fmx; }
        __syncthreads();
        if (tid == 0) { float s = 0; for (int i = 0; i < 16; ++i) s += fsb[i * 4]; xf[14] = s * (1.0f / (float)NW); }
        if (tid == 1) { float m = 1e30f;  for (int i = 0; i < 16; ++i) m = fminf(m, fsb[i * 4 + 1]); xf[2] = m; fctrl[2] = m; }
        if (tid == 2) { float M = -1e30f; for (int i = 0; i < 16; ++i) M = fmaxf(M, fsb[i * 4 + 2]); xf[6] = M; fctrl[3] = M; }
        if (tid == 3) xf[15] = 0.0f;
        __syncthreads();
        // merge privatized copies
        for (int i = tid; i < 4096; i += NT) hist[i] += histB[i];
        __syncthreads();
    }

    // ---- SCAN: in-place hist -> exclusive prefix P; fused rank->bin find ----
    {
        const int b4 = tid * 4;
        const uint32_t v0 = hist[b4], v1 = hist[b4 + 1], v2 = hist[b4 + 2], v3 = hist[b4 + 3];
        const uint32_t s = v0 + v1 + v2 + v3;
        uint32_t p = s;
        #pragma unroll
        for (int off = 1; off < 64; off <<= 1) {
            uint32_t t = __shfl_up(p, off);
            if (lane >= off) p += t;
        }
        if (lane == 63) sbuf[wv] = p;
        __syncthreads();
        if (tid == 0) {
            uint32_t acc = 0;
            for (int i = 0; i < 16; ++i) { uint32_t t = sbuf[i]; sbuf[16 + i] = acc; acc += t; }
        }
        __syncthreads();
        const uint32_t excl = sbuf[16 + wv] + p - s;
        uint32_t ppA[5];
        ppA[0] = excl; ppA[1] = excl + v0; ppA[2] = ppA[1] + v1; ppA[3] = ppA[2] + v2; ppA[4] = ppA[3] + v3;
        hist[b4] = ppA[0]; hist[b4 + 1] = ppA[1]; hist[b4 + 2] = ppA[2]; hist[b4 + 3] = ppA[3];
        const uint32_t RANKS[6] = {65535u, 65536u, 131071u, 131072u, 196607u, 196608u};
        #pragma unroll
        for (int c = 0; c < 4; ++c) {
            #pragma unroll
            for (int q = 0; q < 6; ++q) {
                const uint32_t r = RANKS[q];
                if (ppA[c] <= r && r < ppA[c + 1]) {
                    ctrl[12 + q] = (uint32_t)(b4 + c);   // bin
                    ctrl[18 + q] = r - ppA[c];           // rem within bin
                    ctrl[48 + q] = ppA[c + 1] - ppA[c];  // bin count
                }
            }
        }
        __syncthreads();
    }

    // ---- dedup rank bins; exact-packed seg bases; init cursors/flags ----
    if (tid == 0) {
        uint32_t ndl = 0, fail = 0;
        #pragma unroll
        for (int q = 0; q < 6; ++q) {
            const uint32_t b = ctrl[12 + q];
            int jf = -1;
            for (uint32_t t = 0; t < ndl; ++t) if (ctrl[24 + t] == b) { jf = (int)t; break; }
            if (jf < 0) {
                jf = (int)ndl;
                ctrl[24 + ndl] = b;
                ctrl[30 + ndl] = ctrl[48 + q];
                ndl++;
            }
            ctrl[36 + q] = (uint32_t)jf;
        }
        uint32_t off = 0;
        for (uint32_t t = 0; t < ndl; ++t) {
            ctrl[54 + t] = off;
            if (ctrl[30 + t] > QCAP) fail = 1;
            off += ctrl[30 + t];
        }
        if (off > 6144u) fail = 1;                         // keep >= 6144 MAD slots
        if (ctrl[14] == 0u || ctrl[14] == 4095u) fail = 1; // med in clamped bin
        ctrl[60] = off;   // MAD region base
        ctrl[10] = ndl;
        ctrl[11] = fail;
        #pragma unroll
        for (int j = 0; j < 6; ++j) ctrl[j] = 0;           // quantile cursors
        ctrl[6] = 0;  // MAD cursor
        ctrl[7] = 0;  // c_lo
        ctrl[8] = 0;  // n2theta
        ctrl[9] = 0;  // n2c
        ctrl[48] = 0xFFFFFFFFu; ctrl[49] = 0xFFFFFFFFu;    // window jlo/jhi
    }
    __syncthreads();
    if (ctrl[11]) { fb_path(p4, xf, hist, segs, sbuf, out2, tid); return; }

    const float wbin = 1.0f / bsc;
    const uint32_t m0 = ctrl[14];

    // ---- zero candidate-bin byte table + MAD window bounds from P (parallel) ----
    sbuf[tid] = 0;
    {
        const float mLf = blo + (float)m0 * wbin;
        const float mRf = mLf + wbin;
        #pragma unroll
        for (int c = 0; c < 4; ++c) {
            const int j = tid * 4 + c;
            const float tau = (float)j * wbin;
            const uint32_t up_j = wup(mLf, mRf, tau, blo, bsc, hist);
            if (up_j <= 131071u) {
                bool bnd = (j == 4095);
                if (!bnd) bnd = (wup(mLf, mRf, (float)(j + 1) * wbin, blo, bsc, hist) > 131071u);
                if (bnd) ctrl[48] = (uint32_t)j;
            }
            const uint32_t lo_j = wlow(mLf, mRf, tau, blo, bsc, hist);
            if (lo_j >= 131072u) {
                bool bnd = (j == 0);
                if (!bnd) bnd = (wlow(mLf, mRf, (float)(j - 1) * wbin, blo, bsc, hist) < 131072u);
                if (bnd) ctrl[49] = (uint32_t)j;
            }
        }
    }
    __syncthreads();
    if (tid < (int)ctrl[10]) ((uint8_t*)sbuf)[ctrl[24 + tid]] = (uint8_t)(tid + 1);
    // Padded window (R1 post-mortem): Awin=(jlo-2)w, Bwin=(jhi+3)w give the
    // containment checks provable slack + 1 bin of float-edge fuzz each side.
    const uint32_t jlo = ctrl[48], jhi = ctrl[49];
    float Awin = -1.0f;
    if (jlo != 0xFFFFFFFFu && jlo >= 2u) Awin = (float)(jlo - 2u) * wbin;
    float Bwin = (jhi == 0xFFFFFFFFu) ? 3.0e38f : (float)(jhi + 3u) * wbin;
    Bwin = fmaxf(Bwin, Awin + 3.0f * wbin);
    const float mtld = blo + ((float)m0 + 0.5f) * wbin;  // |med - mtld| <= w/2
    const uint32_t madbase = ctrl[60];
    __syncthreads();

    // ---- S2: single combined sweep — quantile candidates + MAD window + c_lo ----
    uint32_t myclo = 0;
    {
        const uint8_t* tbl = (const uint8_t*)sbuf;
        for (int it = 0; it < 64; it += 8) {
            float4 a8[8];
            #pragma unroll
            for (int j = 0; j < 8; ++j) a8[j] = p4[tid + (it + j) * NT];
            #pragma unroll
            for (int j = 0; j < 8; ++j) {
                float xs[4] = {a8[j].x, a8[j].y, a8[j].z, a8[j].w};
                #pragma unroll
                for (int c = 0; c < 4; ++c) {
                    float x = xs[c];
                    uint32_t m = tbl[binof(x, blo, bsc)];
                    if (m) {
                        uint32_t jj = m - 1u;
                        uint32_t pos = atomicAdd(&ctrl[jj], 1u);
                        if (pos < ctrl[30 + jj]) segs[ctrl[54 + jj] + pos] = mono(x);
                    }
                    float u = fabsf(x - mtld);
                    if (u <= Awin) myclo++;
                    else if (u <= Bwin) {
                        uint32_t pos = atomicAdd(&ctrl[6], 1u);
                        uint32_t slot = madbase + pos;
                        if (slot < SEGS_CAP) segs[slot] = __float_as_uint(x);
                    }
                }
            }
        }
    }
    __syncthreads();
    #pragma unroll
    for (int off = 32; off > 0; off >>= 1) myclo += __shfl_down(myclo, off);
    if (lane == 0) sbuf[wv] = myclo;
    __syncthreads();
    if (tid == 0) {
        uint32_t clo = 0;
        for (int i = 0; i < 16; ++i) clo += sbuf[i];
        ctrl[7] = clo;
        uint32_t fail = 0;
        const uint32_t ndl = ctrl[10];
        for (uint32_t j = 0; j < ndl; ++j) if (ctrl[j] != ctrl[30 + j]) fail = 1;
        if (ctrl[6] > SEGS_CAP - madbase) fail = 1;
        ctrl[11] = fail;
    }
    __syncthreads();
    if (ctrl[11]) { fb_path(p4, xf, hist, segs, sbuf, out2, tid); return; }

    // ---- all-pairs rank select: all 6 quantile ranks, one pass per dedup segment ----
    {
        const uint32_t ndl = ctrl[10];
        for (uint32_t j = 0; j < ndl; ++j) {
            const uint32_t cnt = ctrl[j];
            const uint32_t base = ctrl[54 + j];
            if ((uint32_t)tid < cnt) {
                const uint32_t key = segs[base + tid];
                uint32_t r = 0;
                for (uint32_t i = 0; i < cnt; ++i) {
                    const uint32_t ki = segs[base + i];
                    r += (ki < key || (ki == key && i < (uint32_t)tid)) ? 1u : 0u;
                }
                #pragma unroll
                for (int q = 0; q < 6; ++q)
                    if (ctrl[36 + q] == j && ctrl[18 + q] == r) ctrl[42 + q] = key;
            }
        }
    }
    __syncthreads();
    const float med = unmono(ctrl[44]);
    if (tid == 0) {
        xf[0] = med;
        xf[3] = 0.25f * unmono(ctrl[42]) + 0.75f * unmono(ctrl[43]);
        xf[4] = 0.5f  * (med + unmono(ctrl[45]));
        xf[5] = 0.75f * unmono(ctrl[46]) + 0.25f * unmono(ctrl[47]);
    }

    // ---- MAD: convert window x -> t = |x-med|, verify containment, radix select ----
    const uint32_t mcnt = ctrl[6];
    const float thq = Awin + wbin;
    const float tcq = Bwin - 2.0f * wbin;
    uint32_t n2t = 0, n2c = 0;
    for (uint32_t i = (uint32_t)tid; i < mcnt; i += NT) {
        float x = __uint_as_float(segs[madbase + i]);
        float t = fabsf(x - med);
        segs[madbase + i] = __float_as_uint(t);   // t >= 0: uint order == float order
        n2t += (t <= thq) ? 1u : 0u;
        n2c += (t <= tcq) ? 1u : 0u;
    }
    #pragma unroll
    for (int off = 32; off > 0; off >>= 1) {
        n2t += __shfl_down(n2t, off);
        n2c += __shfl_down(n2c, off);
    }
    if (lane == 0) { atomicAdd(&ctrl[8], n2t); atomicAdd(&ctrl[9], n2c); }
    __syncthreads();
    if (tid == 0) {
        const uint32_t clo = ctrl[7];
        uint32_t fail = 0;
        if (clo > 131071u) fail = 1;
        if (clo + ctrl[8] > 131071u) fail = 1;          // count(t<=theta) <= K => MAD > theta
        if (clo + ctrl[9] < 131072u) fail = 1;          // count(t<=tau_c) >= K+1 => MAD <= tau_c
        if (!fail && (131071u - clo) >= mcnt) fail = 1; // target rank inside window
        ctrl[11] = fail;
    }
    __syncthreads();
    if (ctrl[11]) { fb_path(p4, xf, hist, segs, sbuf, out2, tid); return; }
    const uint32_t kR = 131071u - ctrl[7];
    uint32_t madu = seg_select(segs + madbase, mcnt, kR, hist, sbuf, out2, tid);
    if (tid == 0) xf[1] = __uint_as_float(madu);
}

// ---------- fully fused: b-sort + w-stats + MLP head, one block per (l,b) row ----------
// LDS ~87 KB: guarantees 1 block/CU (prevents 2-block packing that would
// serialize two 2MB-sweep blocks on one CU while other CUs idle).
__global__ __launch_bounds__(NT) void fused_kernel(
    const float* __restrict__ wsrc, const float* __restrict__ bsrc,
    const float* __restrict__ fc1_w, const float* __restrict__ fc1_b,
    const float* __restrict__ ln_w,  const float* __restrict__ ln_b,
    const float* __restrict__ gate_w, const float* __restrict__ gate_b,
    const float* __restrict__ fco_w,  const float* __restrict__ fco_b,
    const float* __restrict__ scale,  float* __restrict__ out) {
    const int row = blockIdx.x;
    const int tid = threadIdx.x;
    const int l = row >> 6;
    __shared__ uint32_t hist[4096];
    __shared__ uint32_t histB[4096];
    __shared__ uint32_t sbuf[1024];
    __shared__ uint32_t segs[SEGS_CAP];
    __shared__ uint32_t ctrl[64];
    __shared__ float fctrl[8];
    __shared__ float xf[16], hm[64], hg[64], st2[2];

    // ---- b-part: sort own row's 512 biases (reuses segs as float scratch) ----
    {
        float* a = (float*)segs;
        float* d = ((float*)segs) + 512;
        const float* p = bsrc + (size_t)row * 512;
        if (tid < 512) a[tid] = p[tid];
        bitonic512w(a, tid);
        const float bmed = a[255];
        if (tid == 0) {
            xf[7]  = bmed;
            xf[9]  = a[0];
            xf[10] = 0.25f * a[127] + 0.75f * a[128];
            xf[11] = 0.5f  * (a[255] + a[256]);
            xf[12] = 0.75f * a[383] + 0.25f * a[384];
            xf[13] = a[511];
        }
        __syncthreads();
        if (tid < 512) d[tid] = fabsf(a[tid] - bmed);
        bitonic512w(d, tid);
        if (tid == 0) xf[8] = d[255];
        __syncthreads();
    }

    // ---- w-stats (2 full sweeps; fallback-guarded) ----
    wstats_body((const float4*)(wsrc + (size_t)row * NW), xf,
                hist, histB, sbuf, segs, ctrl, fctrl, tid);
    __syncthreads();

    // ---- MLP head on LDS-resident features ----
    if (tid == 0) {
        float mu = 0.f;
        for (int i = 0; i < 16; ++i) mu += xf[i];
        mu *= (1.f / 16.f);
        float var = 0.f;
        for (int i = 0; i < 16; ++i) { float dd = xf[i] - mu; var += dd * dd; }
        var *= (1.f / 16.f);
        st2[0] = mu; st2[1] = rsqrtf(var + 1e-5f);
    }
    __syncthreads();
    if (tid < 16) xf[tid] = (xf[tid] - st2[0]) * st2[1];
    __syncthreads();
    if (tid < 64) {
        const float* wv = fc1_w + ((size_t)l * 64 + tid) * 16;
        float acc = fc1_b[l * 64 + tid];
        #pragma unroll
        for (int i = 0; i < 16; ++i) acc += xf[i] * wv[i];
        hm[tid] = acc;
    }
    __syncthreads();
    if (tid == 0) {
        float mu = 0.f;
        for (int i = 0; i < 64; ++i) mu += hm[i];
        mu *= (1.f / 64.f);
        float var = 0.f;
        for (int i = 0; i < 64; ++i) { float dd = hm[i] - mu; var += dd * dd; }
        var *= (1.f / 64.f);
        st2[0] = mu; st2[1] = rsqrtf(var + 1e-5f);
    }
    __syncthreads();
    if (tid < 64) {
        float v = (hm[tid] - st2[0]) * st2[1] * ln_w[l * 64 + tid] + ln_b[l * 64 + tid];
        hm[tid] = 0.5f * v * (1.0f + erff(v * 0.70710678118654752f));
    }
    __syncthreads();
    if (tid < 64) {
        const float* wv = gate_w + ((size_t)l * 64 + tid) * 64;
        float acc = gate_b[l * 64 + tid];
        #pragma unroll
        for (int i = 0; i < 64; ++i) acc += hm[i] * wv[i];
        float g = 1.0f / (1.0f + expf(-acc));
        hg[tid] = hm[tid] * g;
    }
    __syncthreads();
    const float sc = scale[l];
    for (int o = tid; o < 512; o += NT) {
        const float* wv = fco_w + ((size_t)l * 512 + o) * 64;
        float acc = fco_b[l * 512 + o];
        #pragma unroll
        for (int i = 0; i < 64; ++i) acc += hg[i] * wv[i];
        out[(size_t)row * 512 + o] = sinf(acc) * sc + 1.0f;
    }
}

extern "C" void kernel_launch(void* const* d_in, const int* in_sizes, int n_in,
                              void* d_out, int out_size, void* d_ws, size_t ws_size,
                              hipStream_t stream) {
    const float* ws_in  = (const float*)d_in[0];
    const float* bs_in  = (const float*)d_in[1];
    const float* fc1_w  = (const float*)d_in[4];
    const float* fc1_b  = (const float*)d_in[5];
    const float* ln_w   = (const float*)d_in[6];
    const float* ln_b   = (const float*)d_in[7];
    const float* gate_w = (const float*)d_in[8];
    const float* gate_b = (const float*)d_in[9];
    const float* fco_w  = (const float*)d_in[10];
    const float* fco_b  = (const float*)d_in[11];
    const float* scale  = (const float*)d_in[12];
    float* out  = (float*)d_out;

    hipLaunchKernelGGL(fused_kernel, dim3(NROW), dim3(NT), 0, stream,
                       ws_in, bs_in, fc1_w, fc1_b, ln_w, ln_b, gate_w, gate_b,
                       fco_w, fco_b, scale, out);
}

// Round 5
// 420.437 us; speedup vs baseline: 1.0093x; 1.0093x over previous
//
#include <hip/hip_runtime.h>
#include <cstdint>

#define NROW 192
#define NW   262144
#define NT   1024
#define QCAP 1024
#define SEGS_CAP 12288

// ---------- monotone float<->uint transform (total order) ----------
__device__ __forceinline__ uint32_t mono(float x) {
    uint32_t u = __float_as_uint(x);
    return (u & 0x80000000u) ? ~u : (u | 0x80000000u);
}
__device__ __forceinline__ float unmono(uint32_t u) {
    uint32_t v = (u & 0x80000000u) ? (u & 0x7FFFFFFFu) : ~u;
    return __uint_as_float(v);
}
// linear-in-value bin; MUST be the same code in hist and collect sweeps
__device__ __forceinline__ int binof(float x, float lo, float s) {
    float d = (x - lo) * s;
    d = fminf(fmaxf(d, 0.0f), 4095.0f);
    return (int)d;
}

// ---------- block "find bin containing rank" ----------
__device__ void block_select(const uint32_t* hist, int nb, uint32_t rank,
                             uint32_t* sbuf, volatile uint32_t* out, int tid) {
    int per = (nb + NT - 1) / NT;
    int base = tid * per;
    uint32_t s = 0;
    for (int i = 0; i < per; ++i) { int idx = base + i; if (idx < nb) s += hist[idx]; }
    uint32_t p = s;
    int lane = tid & 63;
    #pragma unroll
    for (int off = 1; off < 64; off <<= 1) {
        uint32_t v = __shfl_up(p, off);
        if (lane >= off) p += v;
    }
    int w = tid >> 6;
    if (lane == 63) sbuf[w] = p;
    __syncthreads();
    if (tid == 0) {
        uint32_t acc = 0;
        for (int i = 0; i < 16; ++i) { uint32_t t = sbuf[i]; sbuf[16 + i] = acc; acc += t; }
    }
    __syncthreads();
    uint32_t excl = sbuf[16 + w] + p - s;
    if (rank >= excl && rank < excl + s) {
        uint32_t rem = rank - excl;
        for (int i = 0; i < per; ++i) {
            int idx = base + i;
            if (idx >= nb) break;
            uint32_t c = hist[idx];
            if (rem < c) { out[0] = (uint32_t)idx; out[1] = rem; break; }
            rem -= c;
        }
    }
    __syncthreads();
}

// ---------- exact rank-select among seg[0..cnt) keys, 3-pass LDS radix 11/11/10 ----------
__device__ uint32_t seg_select(const uint32_t* seg, uint32_t cnt, uint32_t rank,
                               uint32_t* hist2, uint32_t* sbuf,
                               volatile uint32_t* out2, int tid) {
    for (int i = tid; i < 2048; i += NT) hist2[i] = 0;
    __syncthreads();
    for (uint32_t i = tid; i < cnt; i += NT) atomicAdd(&hist2[seg[i] >> 21], 1u);
    __syncthreads();
    block_select(hist2, 2048, rank, sbuf, out2, tid);
    uint32_t b1 = out2[0], r1 = out2[1];
    __syncthreads();
    for (int i = tid; i < 2048; i += NT) hist2[i] = 0;
    __syncthreads();
    for (uint32_t i = tid; i < cnt; i += NT) {
        uint32_t k = seg[i];
        if ((k >> 21) == b1) atomicAdd(&hist2[(k >> 10) & 2047u], 1u);
    }
    __syncthreads();
    block_select(hist2, 2048, r1, sbuf, out2, tid);
    uint32_t b2 = out2[0], r2 = out2[1];
    __syncthreads();
    for (int i = tid; i < 1024; i += NT) hist2[i] = 0;
    __syncthreads();
    for (uint32_t i = tid; i < cnt; i += NT) {
        uint32_t k = seg[i];
        if ((k >> 21) == b1 && ((k >> 10) & 2047u) == b2)
            atomicAdd(&hist2[k & 1023u], 1u);
    }
    __syncthreads();
    block_select(hist2, 1024, r2, sbuf, out2, tid);
    uint32_t b3 = out2[0];
    __syncthreads();
    return (b1 << 21) + (b2 << 10) + b3;
}

// ---------- fallback: finish a rank with 2 global sweeps (12-bit mono, proven) ----------
__device__ uint32_t refine_global(const float4* p4, float med, int mode,
                                  uint32_t b1, uint32_t rem,
                                  uint32_t* hist2, uint32_t* sbuf,
                                  volatile uint32_t* out2, int tid) {
    for (int i = tid; i < 2048; i += NT) hist2[i] = 0;
    __syncthreads();
    for (int it = 0; it < 64; ++it) {
        float4 v = p4[tid + it * NT];
        float xs[4] = {v.x, v.y, v.z, v.w};
        #pragma unroll
        for (int c = 0; c < 4; ++c) {
            uint32_t u = mode ? __float_as_uint(fabsf(xs[c] - med)) : mono(xs[c]);
            if ((u >> 20) == b1) atomicAdd(&hist2[(u >> 9) & 2047u], 1u);
        }
    }
    __syncthreads();
    block_select(hist2, 2048, rem, sbuf, out2, tid);
    uint32_t b2 = out2[0], r2 = out2[1];
    __syncthreads();
    for (int i = tid; i < 512; i += NT) hist2[i] = 0;
    __syncthreads();
    for (int it = 0; it < 64; ++it) {
        float4 v = p4[tid + it * NT];
        float xs[4] = {v.x, v.y, v.z, v.w};
        #pragma unroll
        for (int c = 0; c < 4; ++c) {
            uint32_t u = mode ? __float_as_uint(fabsf(xs[c] - med)) : mono(xs[c]);
            if ((u >> 20) == b1 && ((u >> 9) & 2047u) == b2)
                atomicAdd(&hist2[u & 511u], 1u);
        }
    }
    __syncthreads();
    block_select(hist2, 512, r2, sbuf, out2, tid);
    uint32_t b3 = out2[0];
    __syncthreads();
    return (b1 << 20) + (b2 << 9) + b3;
}

// ---------- fallback path: full 12-bit 3-level select (slow, always correct) ----------
__device__ void fb_path(const float4* p4, float* xf,
                        uint32_t* hist, uint32_t* hist2, uint32_t* sbuf,
                        volatile uint32_t* out2, int tid) {
    const uint32_t RANK6[6] = {65535u, 65536u, 131071u, 131072u, 196607u, 196608u};
    for (int i = tid; i < 4096; i += NT) hist[i] = 0;
    __syncthreads();
    for (int it = 0; it < 64; ++it) {
        float4 v = p4[tid + it * NT];
        float xs[4] = {v.x, v.y, v.z, v.w};
        #pragma unroll
        for (int c = 0; c < 4; ++c) atomicAdd(&hist[mono(xs[c]) >> 20], 1u);
    }
    __syncthreads();
    uint32_t bins[6], rems[6];
    for (int k = 0; k < 6; ++k) {
        block_select(hist, 4096, RANK6[k], sbuf, out2, tid);
        bins[k] = out2[0]; rems[k] = out2[1];
        __syncthreads();
    }
    float svv[6];
    for (int k = 0; k < 6; ++k)
        svv[k] = unmono(refine_global(p4, 0.f, 0, bins[k], rems[k], hist2, sbuf, out2, tid));
    if (tid == 0) {
        xf[0] = svv[2];
        xf[3] = 0.25f * svv[0] + 0.75f * svv[1];
        xf[4] = 0.5f  * (svv[2] + svv[3]);
        xf[5] = 0.75f * svv[4] + 0.25f * svv[5];
    }
    float med = svv[2];
    __syncthreads();
    for (int i = tid; i < 4096; i += NT) hist[i] = 0;
    __syncthreads();
    for (int it = 0; it < 64; ++it) {
        float4 v = p4[tid + it * NT];
        float xs[4] = {v.x, v.y, v.z, v.w};
        #pragma unroll
        for (int c = 0; c < 4; ++c)
            atomicAdd(&hist[__float_as_uint(fabsf(xs[c] - med)) >> 20], 1u);
    }
    __syncthreads();
    block_select(hist, 4096, 131071u, sbuf, out2, tid);
    uint32_t mb = out2[0], mr = out2[1];
    __syncthreads();
    uint32_t mu = refine_global(p4, med, 1, mb, mr, hist2, sbuf, out2, tid);
    if (tid == 0) xf[1] = __uint_as_float(mu);
}

// ---------- prefix-sum helpers (hist holds exclusive prefix P after scan) ----------
__device__ __forceinline__ uint32_t Pv(const uint32_t* P, int k) {
    return (k >= 4096) ? (uint32_t)NW : P[k];
}
__device__ __forceinline__ uint32_t wup(float mL, float mR, float tau,
                                        float blo, float bsc, const uint32_t* P) {
    const int bR = binof(mR + tau, blo, bsc);
    const int bL = binof(mL - tau, blo, bsc);
    return Pv(P, bR + 1) - P[bL];
}
__device__ __forceinline__ uint32_t wlow(float mL, float mR, float tau,
                                         float blo, float bsc, const uint32_t* P) {
    const int bR = binof(mL + tau, blo, bsc);
    const int bL = binof(mR - tau, blo, bsc);
    const uint32_t a = P[bR];
    const uint32_t b = Pv(P, bL + 1);
    return (a > b) ? (a - b) : 0u;
}

// ---------- barrier-free 512-element bitonic sort in ONE wave's registers ----------
// 8 values/lane, global index i = r*64 + lane. Ascending. 0 barriers, 0 LDS.
__device__ __forceinline__ void regsort512(float v[8], int lane) {
    #pragma unroll
    for (int kk = 1; kk <= 9; ++kk) {
        const int k = 1 << kk;
        #pragma unroll
        for (int jj = kk - 1; jj >= 0; --jj) {
            const int j = 1 << jj;
            if (j >= 64) {
                const int jr = j >> 6;
                const int kr = k >> 6;          // k >= 128 in this branch
                #pragma unroll
                for (int r = 0; r < 8; ++r) {
                    if ((r & jr) == 0) {
                        const bool up = ((r & kr) == 0);
                        float x = v[r], y = v[r | jr];
                        float mn = fminf(x, y), mx = fmaxf(x, y);
                        v[r]      = up ? mn : mx;
                        v[r | jr] = up ? mx : mn;
                    }
                }
            } else {
                #pragma unroll
                for (int r = 0; r < 8; ++r) {
                    const int i = (r << 6) | lane;
                    const bool up = ((i & k) == 0);
                    const bool lower = ((lane & j) == 0);
                    float x = v[r];
                    float y = __shfl_xor(x, j);
                    v[r] = (lower == up) ? fminf(x, y) : fmaxf(x, y);
                }
            }
        }
    }
}

// ---------- w-row robust stats body: 2 full sweeps, writes xf[0..6,14,15] ----------
__device__ void wstats_body(const float4* __restrict__ p4, float* xf,
                            uint32_t* hist, uint32_t* histB,
                            uint32_t* histC, uint32_t* histD,
                            uint32_t* sbuf, uint32_t* segs,
                            uint32_t* ctrl, float* fctrl, int tid) {
    const int lane = tid & 63, wv = tid >> 6;
    float* fsb = (float*)sbuf;
    volatile uint32_t* out2 = (volatile uint32_t*)(ctrl + 62);

    // ---- P0: contiguous prefix sample (32768 floats) -> linear-bin range ----
    {
        float smin = 1e30f, smax = -1e30f;
        #pragma unroll
        for (int k = 0; k < 8; ++k) {
            float4 v = p4[tid + k * NT];
            smin = fminf(smin, fminf(fminf(v.x, v.y), fminf(v.z, v.w)));
            smax = fmaxf(smax, fmaxf(fmaxf(v.x, v.y), fmaxf(v.z, v.w)));
        }
        #pragma unroll
        for (int off = 32; off > 0; off >>= 1) {
            smin = fminf(smin, __shfl_down(smin, off));
            smax = fmaxf(smax, __shfl_down(smax, off));
        }
        if (lane == 0) { fsb[wv * 2] = smin; fsb[wv * 2 + 1] = smax; }
        __syncthreads();
        if (tid == 0) {
            float mn = 1e30f, mx = -1e30f;
            for (int i = 0; i < 16; ++i) { mn = fminf(mn, fsb[i * 2]); mx = fmaxf(mx, fsb[i * 2 + 1]); }
            float span = mx - mn;
            float lo = mn - 0.0625f * span;
            float s = (span > 0.f) ? 4096.0f / (span * 1.125f) : 0.0f;
            fctrl[0] = lo; fctrl[1] = s;
        }
        __syncthreads();
    }
    const float blo = fctrl[0], bsc = fctrl[1];

    // ---- S1: full sweep — 4-way privatized hist + sum + exact min/max ----
    for (int i = tid; i < 4096; i += NT) { hist[i] = 0; histB[i] = 0; histC[i] = 0; histD[i] = 0; }
    __syncthreads();
    {
        const int hs = wv & 3;
        uint32_t* hsel = (hs == 0) ? hist : ((hs == 1) ? histB : ((hs == 2) ? histC : histD));
        float sum = 0.f, fmn = 1e30f, fmx = -1e30f;
        for (int it = 0; it < 64; it += 16) {
            float4 a8[16];
            #pragma unroll
            for (int j = 0; j < 16; ++j) a8[j] = p4[tid + (it + j) * NT];
            #pragma unroll
            for (int j = 0; j < 16; ++j) {
                float xs[4] = {a8[j].x, a8[j].y, a8[j].z, a8[j].w};
                #pragma unroll
                for (int c = 0; c < 4; ++c) {
                    float x = xs[c];
                    sum += x;
                    fmn = fminf(fmn, x);
                    fmx = fmaxf(fmx, x);
                    atomicAdd(&hsel[binof(x, blo, bsc)], 1u);
                }
            }
        }
        #pragma unroll
        for (int off = 32; off > 0; off >>= 1) {
            sum += __shfl_down(sum, off);
            fmn = fminf(fmn, __shfl_down(fmn, off));
            fmx = fmaxf(fmx, __shfl_down(fmx, off));
        }
        __syncthreads();
        if (lane == 0) { fsb[wv * 4] = sum; fsb[wv * 4 + 1] = fmn; fsb[wv * 4 + 2] = fmx; }
        __syncthreads();
        if (tid == 0) { float s = 0; for (int i = 0; i < 16; ++i) s += fsb[i * 4]; xf[14] = s * (1.0f / (float)NW); }
        if (tid == 1) { float m = 1e30f;  for (int i = 0; i < 16; ++i) m = fminf(m, fsb[i * 4 + 1]); xf[2] = m; fctrl[2] = m; }
        if (tid == 2) { float M = -1e30f; for (int i = 0; i < 16; ++i) M = fmaxf(M, fsb[i * 4 + 2]); xf[6] = M; fctrl[3] = M; }
        if (tid == 3) xf[15] = 0.0f;
        __syncthreads();
        for (int i = tid; i < 4096; i += NT) hist[i] += histB[i] + histC[i] + histD[i];
        __syncthreads();
    }

    // ---- SCAN: in-place hist -> exclusive prefix P; fused rank->bin find ----
    {
        const int b4 = tid * 4;
        const uint32_t v0 = hist[b4], v1 = hist[b4 + 1], v2 = hist[b4 + 2], v3 = hist[b4 + 3];
        const uint32_t s = v0 + v1 + v2 + v3;
        uint32_t p = s;
        #pragma unroll
        for (int off = 1; off < 64; off <<= 1) {
            uint32_t t = __shfl_up(p, off);
            if (lane >= off) p += t;
        }
        if (lane == 63) sbuf[wv] = p;
        __syncthreads();
        if (tid == 0) {
            uint32_t acc = 0;
            for (int i = 0; i < 16; ++i) { uint32_t t = sbuf[i]; sbuf[16 + i] = acc; acc += t; }
        }
        __syncthreads();
        const uint32_t excl = sbuf[16 + wv] + p - s;
        uint32_t ppA[5];
        ppA[0] = excl; ppA[1] = excl + v0; ppA[2] = ppA[1] + v1; ppA[3] = ppA[2] + v2; ppA[4] = ppA[3] + v3;
        hist[b4] = ppA[0]; hist[b4 + 1] = ppA[1]; hist[b4 + 2] = ppA[2]; hist[b4 + 3] = ppA[3];
        const uint32_t RANKS[6] = {65535u, 65536u, 131071u, 131072u, 196607u, 196608u};
        #pragma unroll
        for (int c = 0; c < 4; ++c) {
            #pragma unroll
            for (int q = 0; q < 6; ++q) {
                const uint32_t r = RANKS[q];
                if (ppA[c] <= r && r < ppA[c + 1]) {
                    ctrl[12 + q] = (uint32_t)(b4 + c);   // bin
                    ctrl[18 + q] = r - ppA[c];           // rem within bin
                    ctrl[48 + q] = ppA[c + 1] - ppA[c];  // bin count
                }
            }
        }
        __syncthreads();
    }

    // ---- dedup rank bins; exact-packed seg bases; init cursors/flags ----
    if (tid == 0) {
        uint32_t ndl = 0, fail = 0;
        #pragma unroll
        for (int q = 0; q < 6; ++q) {
            const uint32_t b = ctrl[12 + q];
            int jf = -1;
            for (uint32_t t = 0; t < ndl; ++t) if (ctrl[24 + t] == b) { jf = (int)t; break; }
            if (jf < 0) {
                jf = (int)ndl;
                ctrl[24 + ndl] = b;
                ctrl[30 + ndl] = ctrl[48 + q];
                ndl++;
            }
            ctrl[36 + q] = (uint32_t)jf;
        }
        uint32_t off = 0;
        for (uint32_t t = 0; t < ndl; ++t) {
            ctrl[54 + t] = off;
            if (ctrl[30 + t] > QCAP) fail = 1;
            off += ctrl[30 + t];
        }
        if (off > 6144u) fail = 1;                         // keep >= 6144 MAD slots
        if (ctrl[14] == 0u || ctrl[14] == 4095u) fail = 1; // med in clamped bin
        ctrl[60] = off;   // MAD region base
        ctrl[10] = ndl;
        ctrl[11] = fail;
        #pragma unroll
        for (int j = 0; j < 6; ++j) ctrl[j] = 0;           // quantile cursors
        ctrl[6] = 0;  // MAD cursor
        ctrl[7] = 0;  // c_lo
        ctrl[8] = 0;  // n2theta
        ctrl[9] = 0;  // n2c
        ctrl[48] = 0xFFFFFFFFu; ctrl[49] = 0xFFFFFFFFu;    // window jlo/jhi
    }
    __syncthreads();
    if (ctrl[11]) { fb_path(p4, xf, hist, segs, sbuf, out2, tid); return; }

    const float wbin = 1.0f / bsc;
    const uint32_t m0 = ctrl[14];

    // ---- zero candidate-bin byte table + MAD window bounds from P (parallel) ----
    sbuf[tid] = 0;
    {
        const float mLf = blo + (float)m0 * wbin;
        const float mRf = mLf + wbin;
        #pragma unroll
        for (int c = 0; c < 4; ++c) {
            const int j = tid * 4 + c;
            const float tau = (float)j * wbin;
            const uint32_t up_j = wup(mLf, mRf, tau, blo, bsc, hist);
            if (up_j <= 131071u) {
                bool bnd = (j == 4095);
                if (!bnd) bnd = (wup(mLf, mRf, (float)(j + 1) * wbin, blo, bsc, hist) > 131071u);
                if (bnd) ctrl[48] = (uint32_t)j;
            }
            const uint32_t lo_j = wlow(mLf, mRf, tau, blo, bsc, hist);
            if (lo_j >= 131072u) {
                bool bnd = (j == 0);
                if (!bnd) bnd = (wlow(mLf, mRf, (float)(j - 1) * wbin, blo, bsc, hist) < 131072u);
                if (bnd) ctrl[49] = (uint32_t)j;
            }
        }
    }
    __syncthreads();
    if (tid < (int)ctrl[10]) ((uint8_t*)sbuf)[ctrl[24 + tid]] = (uint8_t)(tid + 1);
    // Padded window (R1 post-mortem): Awin=(jlo-2)w, Bwin=(jhi+3)w give the
    // containment checks provable slack + 1 bin of float-edge fuzz each side.
    const uint32_t jlo = ctrl[48], jhi = ctrl[49];
    float Awin = -1.0f;
    if (jlo != 0xFFFFFFFFu && jlo >= 2u) Awin = (float)(jlo - 2u) * wbin;
    float Bwin = (jhi == 0xFFFFFFFFu) ? 3.0e38f : (float)(jhi + 3u) * wbin;
    Bwin = fmaxf(Bwin, Awin + 3.0f * wbin);
    const float mtld = blo + ((float)m0 + 0.5f) * wbin;  // |med - mtld| <= w/2
    const uint32_t madbase = ctrl[60];
    __syncthreads();

    // ---- S2: single combined sweep — quantile candidates + MAD window + c_lo ----
    uint32_t myclo = 0;
    {
        const uint8_t* tbl = (const uint8_t*)sbuf;
        for (int it = 0; it < 64; it += 16) {
            float4 a8[16];
            #pragma unroll
            for (int j = 0; j < 16; ++j) a8[j] = p4[tid + (it + j) * NT];
            #pragma unroll
            for (int j = 0; j < 16; ++j) {
                float xs[4] = {a8[j].x, a8[j].y, a8[j].z, a8[j].w};
                #pragma unroll
                for (int c = 0; c < 4; ++c) {
                    float x = xs[c];
                    uint32_t m = tbl[binof(x, blo, bsc)];
                    if (m) {
                        uint32_t jj = m - 1u;
                        uint32_t pos = atomicAdd(&ctrl[jj], 1u);
                        if (pos < ctrl[30 + jj]) segs[ctrl[54 + jj] + pos] = mono(x);
                    }
                    float u = fabsf(x - mtld);
                    if (u <= Awin) myclo++;
                    else if (u <= Bwin) {
                        uint32_t pos = atomicAdd(&ctrl[6], 1u);
                        uint32_t slot = madbase + pos;
                        if (slot < SEGS_CAP) segs[slot] = __float_as_uint(x);
                    }
                }
            }
        }
    }
    __syncthreads();
    #pragma unroll
    for (int off = 32; off > 0; off >>= 1) myclo += __shfl_down(myclo, off);
    if (lane == 0) sbuf[wv] = myclo;
    __syncthreads();
    if (tid == 0) {
        uint32_t clo = 0;
        for (int i = 0; i < 16; ++i) clo += sbuf[i];
        ctrl[7] = clo;
        uint32_t fail = 0;
        const uint32_t ndl = ctrl[10];
        for (uint32_t j = 0; j < ndl; ++j) if (ctrl[j] != ctrl[30 + j]) fail = 1;
        if (ctrl[6] > SEGS_CAP - madbase) fail = 1;
        ctrl[11] = fail;
    }
    __syncthreads();
    if (ctrl[11]) { fb_path(p4, xf, hist, segs, sbuf, out2, tid); return; }

    // ---- all-pairs rank select: all 6 quantile ranks, one pass per dedup segment ----
    {
        const uint32_t ndl = ctrl[10];
        for (uint32_t j = 0; j < ndl; ++j) {
            const uint32_t cnt = ctrl[j];
            const uint32_t base = ctrl[54 + j];
            if ((uint32_t)tid < cnt) {
                const uint32_t key = segs[base + tid];
                uint32_t r = 0;
                for (uint32_t i = 0; i < cnt; ++i) {
                    const uint32_t ki = segs[base + i];
                    r += (ki < key || (ki == key && i < (uint32_t)tid)) ? 1u : 0u;
                }
                #pragma unroll
                for (int q = 0; q < 6; ++q)
                    if (ctrl[36 + q] == j && ctrl[18 + q] == r) ctrl[42 + q] = key;
            }
        }
    }
    __syncthreads();
    const float med = unmono(ctrl[44]);
    if (tid == 0) {
        xf[0] = med;
        xf[3] = 0.25f * unmono(ctrl[42]) + 0.75f * unmono(ctrl[43]);
        xf[4] = 0.5f  * (med + unmono(ctrl[45]));
        xf[5] = 0.75f * unmono(ctrl[46]) + 0.25f * unmono(ctrl[47]);
    }

    // ---- MAD: convert window x -> t = |x-med|, verify containment, radix select ----
    const uint32_t mcnt = ctrl[6];
    const float thq = Awin + wbin;
    const float tcq = Bwin - 2.0f * wbin;
    uint32_t n2t = 0, n2c = 0;
    for (uint32_t i = (uint32_t)tid; i < mcnt; i += NT) {
        float x = __uint_as_float(segs[madbase + i]);
        float t = fabsf(x - med);
        segs[madbase + i] = __float_as_uint(t);   // t >= 0: uint order == float order
        n2t += (t <= thq) ? 1u : 0u;
        n2c += (t <= tcq) ? 1u : 0u;
    }
    #pragma unroll
    for (int off = 32; off > 0; off >>= 1) {
        n2t += __shfl_down(n2t, off);
        n2c += __shfl_down(n2c, off);
    }
    if (lane == 0) { atomicAdd(&ctrl[8], n2t); atomicAdd(&ctrl[9], n2c); }
    __syncthreads();
    if (tid == 0) {
        const uint32_t clo = ctrl[7];
        uint32_t fail = 0;
        if (clo > 131071u) fail = 1;
        if (clo + ctrl[8] > 131071u) fail = 1;          // count(t<=theta) <= K => MAD > theta
        if (clo + ctrl[9] < 131072u) fail = 1;          // count(t<=tau_c) >= K+1 => MAD <= tau_c
        if (!fail && (131071u - clo) >= mcnt) fail = 1; // target rank inside window
        ctrl[11] = fail;
    }
    __syncthreads();
    if (ctrl[11]) { fb_path(p4, xf, hist, segs, sbuf, out2, tid); return; }
    const uint32_t kR = 131071u - ctrl[7];
    uint32_t madu = seg_select(segs + madbase, mcnt, kR, hist, sbuf, out2, tid);
    if (tid == 0) xf[1] = __uint_as_float(madu);
}

// ---------- fully fused: reg-bitonic b-sort + w-stats + MLP head ----------
// LDS ~119 KB: 1 block/CU. b-sort is barrier-free (wave 0, registers+shfl).
__global__ __launch_bounds__(NT) void fused_kernel(
    const float* __restrict__ wsrc, const float* __restrict__ bsrc,
    const float* __restrict__ fc1_w, const float* __restrict__ fc1_b,
    const float* __restrict__ ln_w,  const float* __restrict__ ln_b,
    const float* __restrict__ gate_w, const float* __restrict__ gate_b,
    const float* __restrict__ fco_w,  const float* __restrict__ fco_b,
    const float* __restrict__ scale,  float* __restrict__ out) {
    const int row = blockIdx.x;
    const int tid = threadIdx.x;
    const int l = row >> 6;
    __shared__ uint32_t hist[4096];
    __shared__ uint32_t histB[4096];
    __shared__ uint32_t histC[4096];
    __shared__ uint32_t histD[4096];
    __shared__ uint32_t sbuf[1024];
    __shared__ uint32_t segs[SEGS_CAP];
    __shared__ uint32_t ctrl[64];
    __shared__ float fctrl[8];
    __shared__ float xf[16], hm[64], hg[64], st2[2];

    // ---- b-part: wave 0 sorts its row's 512 biases in registers (no barriers) ----
    if (tid < 64) {
        const int lane = tid;
        const float* p = bsrc + (size_t)row * 512;
        float v[8];
        #pragma unroll
        for (int r = 0; r < 8; ++r) v[r] = p[(r << 6) | lane];
        regsort512(v, lane);
        const float a0   = __shfl(v[0], 0);
        const float a127 = __shfl(v[1], 63);
        const float a128 = __shfl(v[2], 0);
        const float a255 = __shfl(v[3], 63);
        const float a256 = __shfl(v[4], 0);
        const float a383 = __shfl(v[5], 63);
        const float a384 = __shfl(v[6], 0);
        const float a511 = __shfl(v[7], 63);
        const float bmed = a255;
        float t[8];
        #pragma unroll
        for (int r = 0; r < 8; ++r) t[r] = fabsf(v[r] - bmed);
        regsort512(t, lane);
        const float d255 = __shfl(t[3], 63);
        if (lane == 0) {
            xf[7]  = bmed;
            xf[8]  = d255;
            xf[9]  = a0;
            xf[10] = 0.25f * a127 + 0.75f * a128;
            xf[11] = 0.5f  * (a255 + a256);
            xf[12] = 0.75f * a383 + 0.25f * a384;
            xf[13] = a511;
        }
    }
    // no barrier needed here: xf[7..13] is read only after wstats_body's barriers

    // ---- w-stats (2 full sweeps; fallback-guarded) ----
    wstats_body((const float4*)(wsrc + (size_t)row * NW), xf,
                hist, histB, histC, histD, sbuf, segs, ctrl, fctrl, tid);
    __syncthreads();

    // ---- MLP head on LDS-resident features ----
    if (tid == 0) {
        float mu = 0.f;
        for (int i = 0; i < 16; ++i) mu += xf[i];
        mu *= (1.f / 16.f);
        float var = 0.f;
        for (int i = 0; i < 16; ++i) { float dd = xf[i] - mu; var += dd * dd; }
        var *= (1.f / 16.f);
        st2[0] = mu; st2[1] = rsqrtf(var + 1e-5f);
    }
    __syncthreads();
    if (tid < 16) xf[tid] = (xf[tid] - st2[0]) * st2[1];
    __syncthreads();
    if (tid < 64) {
        const float* wv = fc1_w + ((size_t)l * 64 + tid) * 16;
        float acc = fc1_b[l * 64 + tid];
        #pragma unroll
        for (int i = 0; i < 16; ++i) acc += xf[i] * wv[i];
        hm[tid] = acc;
    }
    __syncthreads();
    if (tid == 0) {
        float mu = 0.f;
        for (int i = 0; i < 64; ++i) mu += hm[i];
        mu *= (1.f / 64.f);
        float var = 0.f;
        for (int i = 0; i < 64; ++i) { float dd = hm[i] - mu; var += dd * dd; }
        var *= (1.f / 64.f);
        st2[0] = mu; st2[1] = rsqrtf(var + 1e-5f);
    }
    __syncthreads();
    if (tid < 64) {
        float v = (hm[tid] - st2[0]) * st2[1] * ln_w[l * 64 + tid] + ln_b[l * 64 + tid];
        hm[tid] = 0.5f * v * (1.0f + erff(v * 0.70710678118654752f));
    }
    __syncthreads();
    if (tid < 64) {
        const float* wv = gate_w + ((size_t)l * 64 + tid) * 64;
        float acc = gate_b[l * 64 + tid];
        #pragma unroll
        for (int i = 0; i < 64; ++i) acc += hm[i] * wv[i];
        float g = 1.0f / (1.0f + expf(-acc));
        hg[tid] = hm[tid] * g;
    }
    __syncthreads();
    const float sc = scale[l];
    for (int o = tid; o < 512; o += NT) {
        const float* wv = fco_w + ((size_t)l * 512 + o) * 64;
        float acc = fco_b[l * 512 + o];
        #pragma unroll
        for (int i = 0; i < 64; ++i) acc += hg[i] * wv[i];
        out[(size_t)row * 512 + o] = sinf(acc) * sc + 1.0f;
    }
}

extern "C" void kernel_launch(void* const* d_in, const int* in_sizes, int n_in,
                              void* d_out, int out_size, void* d_ws, size_t ws_size,
                              hipStream_t stream) {
    const float* ws_in  = (const float*)d_in[0];
    const float* bs_in  = (const float*)d_in[1];
    const float* fc1_w  = (const float*)d_in[4];
    const float* fc1_b  = (const float*)d_in[5];
    const float* ln_w   = (const float*)d_in[6];
    const float* ln_b   = (const float*)d_in[7];
    const float* gate_w = (const float*)d_in[8];
    const float* gate_b = (const float*)d_in[9];
    const float* fco_w  = (const float*)d_in[10];
    const float* fco_b  = (const float*)d_in[11];
    const float* scale  = (const float*)d_in[12];
    float* out  = (float*)d_out;

    hipLaunchKernelGGL(fused_kernel, dim3(NROW), dim3(NT), 0, stream,
                       ws_in, bs_in, fc1_w, fc1_b, ln_w, ln_b, gate_w, gate_b,
                       fco_w, fco_b, scale, out);
}